// Round 5
// baseline (7347.944 us; speedup 1.0000x reference)
//
#include <hip/hip_runtime.h>

// LTC scan via MFMA. One WG per batch item (64 WGs), 256 thr = 4 waves,
// 1 wave/SIMD (512-VGPR budget, __launch_bounds__(256,1)).
// Per step, z = W_rec·h + W_in·x + b_in + b_rec is a 1x256 x 256x256(+128)
// matvec -> mfma_f32_16x16x32_f16 with the SAME A data broadcast to all 16
// rows (A-frag addr depends only on lane>>4) => every D row equals z: no
// masking, no cross-lane reduction. Wave w owns cols [64w,64w+64) as 4
// 16-col tiles; B-frags (W_rec 128 regs + W_in 64 regs, f16 RTE) stationary.
// h STATE stays f32 in registers; only the MFMA input is f16 (quantization
// does not accumulate in state). Input-proj MFMAs (K=128, 4 steps) run once
// per t with acc preloaded with b_in+b_rec; result reused by both layers.
// h round-trips LDS as f16 in A-permuted order (k=32i+8q+j -> q*64+8i+j) so
// each K-step A-frag is one ds_read_b128; double-buffered, 1 barrier/layer.

typedef _Float16 half8 __attribute__((ext_vector_type(8)));
typedef _Float16 half4 __attribute__((ext_vector_type(4)));
typedef float    f32x4 __attribute__((ext_vector_type(4)));

__device__ __forceinline__ float fast_tanh(float z) {
    float e = __expf(2.0f * z);        // inf-safe
    return 1.0f - 2.0f / (e + 1.0f);
}

// A-perm address: k = 32i + 8q + j  ->  64q + 8i + j   (K=256, h)
__device__ __forceinline__ int hp_addr(int k) {
    return ((k >> 3) & 3) * 64 + (k >> 5) * 8 + (k & 7);
}
// x version (K=128): k = 32i + 8q + j -> 32q + 8i + j
__device__ __forceinline__ int xp_addr(int k) {
    return ((k >> 3) & 3) * 32 + (k >> 5) * 8 + (k & 7);
}

__global__ void __launch_bounds__(256, 1)
ltc_scan(const float* __restrict__ x,      // [B,T,128]
         const float* __restrict__ W_in,   // [256,128]
         const float* __restrict__ b_in,   // [256]
         const float* __restrict__ W_rec,  // [256,256]
         const float* __restrict__ b_rec,  // [256]
         const float* __restrict__ tau,    // [256]
         const int*   __restrict__ num_layers,
         float*       __restrict__ out,    // [B,256]
         int T)
{
    const int b    = blockIdx.x;
    const int tid  = threadIdx.x;
    const int lane = tid & 63;
    const int w    = tid >> 6;     // wave 0..3, owns cols [64w, 64w+64)
    const int n    = lane & 15;    // tile column
    const int q    = lane >> 4;    // k-quad 0..3
    const int L    = num_layers[0];

    __shared__ _Float16 hperm[2][256];
    __shared__ _Float16 xperm[2][128];

    // ---- B-frags: W_rec (4 tiles x 8 K-steps) and W_in (4 x 4), f16 RTE ----
    half8 bh[4][8];
#pragma unroll
    for (int t4 = 0; t4 < 4; ++t4) {
        const int col = 64 * w + 16 * t4 + n;
        const float* rp = &W_rec[col * 256 + 8 * q];
#pragma unroll
        for (int i = 0; i < 8; ++i) {
            float4 v0 = *(const float4*)&rp[32 * i];
            float4 v1 = *(const float4*)&rp[32 * i + 4];
            half8 hv;
            hv[0] = (_Float16)v0.x; hv[1] = (_Float16)v0.y;
            hv[2] = (_Float16)v0.z; hv[3] = (_Float16)v0.w;
            hv[4] = (_Float16)v1.x; hv[5] = (_Float16)v1.y;
            hv[6] = (_Float16)v1.z; hv[7] = (_Float16)v1.w;
            bh[t4][i] = hv;
        }
    }
    half8 bx[4][4];
#pragma unroll
    for (int t4 = 0; t4 < 4; ++t4) {
        const int col = 64 * w + 16 * t4 + n;
        const float* rp = &W_in[col * 128 + 8 * q];
#pragma unroll
        for (int i = 0; i < 4; ++i) {
            float4 v0 = *(const float4*)&rp[32 * i];
            float4 v1 = *(const float4*)&rp[32 * i + 4];
            half8 hv;
            hv[0] = (_Float16)v0.x; hv[1] = (_Float16)v0.y;
            hv[2] = (_Float16)v0.z; hv[3] = (_Float16)v0.w;
            hv[4] = (_Float16)v1.x; hv[5] = (_Float16)v1.y;
            hv[6] = (_Float16)v1.z; hv[7] = (_Float16)v1.w;
            bx[t4][i] = hv;
        }
    }
#pragma unroll
    for (int t4 = 0; t4 < 4; ++t4) {
#pragma unroll
        for (int i = 0; i < 8; ++i) asm volatile("" : "+v"(bh[t4][i]));
#pragma unroll
        for (int i = 0; i < 4; ++i) asm volatile("" : "+v"(bx[t4][i]));
    }

    // ---- per-tile scalars: bias (b_in+b_rec), scale, h state, h LDS addr ----
    float bias[4], sj[4], hj[4];
    int   haddr[4];
#pragma unroll
    for (int t4 = 0; t4 < 4; ++t4) {
        const int col = 64 * w + 16 * t4 + n;
        bias[t4]  = b_in[col] + b_rec[col];
        sj[t4]    = 0.1f / fminf(fmaxf(tau[col], 0.1f), 5.0f);
        hj[t4]    = 0.0f;
        haddr[t4] = hp_addr(col);
    }

    // ---- init: zero h buffer 0, stage x(0) ----
    if (tid < 256) hperm[0][tid] = (_Float16)0.0f;
    const float* xb = x + (size_t)b * T * 128;
    if (tid < 32) {
        float4 xf = *(const float4*)&xb[4 * tid];
        half4 hv;
        hv[0] = (_Float16)xf.x; hv[1] = (_Float16)xf.y;
        hv[2] = (_Float16)xf.z; hv[3] = (_Float16)xf.w;
        *(half4*)&xperm[0][xp_addr(4 * tid)] = hv;
    }
    __syncthreads();

    int hb = 0;
    for (int t = 0; t < T; ++t) {
        // issue x(t+1) global load now; converted/staged at last layer
        const bool ldx = (tid < 32) && (t + 1 < T);
        float4 xf;
        if (ldx) xf = *(const float4*)&xb[(size_t)(t + 1) * 128 + 4 * tid];

        // ---- input-projection MFMAs (once per t), acc seeded with biases ----
        f32x4 px[4];
#pragma unroll
        for (int t4 = 0; t4 < 4; ++t4)
            px[t4] = (f32x4){bias[t4], bias[t4], bias[t4], bias[t4]};
        {
            const _Float16* xsrc = &xperm[t & 1][q * 32];
            half8 ax[4];
#pragma unroll
            for (int i = 0; i < 4; ++i) ax[i] = *(const half8*)&xsrc[8 * i];
#pragma unroll
            for (int i = 0; i < 4; ++i)
#pragma unroll
                for (int t4 = 0; t4 < 4; ++t4)
                    px[t4] = __builtin_amdgcn_mfma_f32_16x16x32_f16(
                        ax[i], bx[t4][i], px[t4], 0, 0, 0);
        }

        for (int l = 0; l < L; ++l) {
            f32x4 acc[4];
#pragma unroll
            for (int t4 = 0; t4 < 4; ++t4) acc[t4] = px[t4];

            const _Float16* hsrc = &hperm[hb][q * 64];
            half8 ah[8];
#pragma unroll
            for (int i = 0; i < 8; ++i) ah[i] = *(const half8*)&hsrc[8 * i];
#pragma unroll
            for (int i = 0; i < 8; ++i)
#pragma unroll
                for (int t4 = 0; t4 < 4; ++t4)
                    acc[t4] = __builtin_amdgcn_mfma_f32_16x16x32_f16(
                        ah[i], bh[t4][i], acc[t4], 0, 0, 0);

            // ---- epilogue: all D-rows identical -> use row component 0.
            // Replicated across q-groups; state hj stays f32.
#pragma unroll
            for (int t4 = 0; t4 < 4; ++t4) {
                float z = acc[t4][0];
                float a = fast_tanh(z);
                hj[t4] += sj[t4] * (a - hj[t4]);
            }
            if (q == 0) {
#pragma unroll
                for (int t4 = 0; t4 < 4; ++t4)
                    hperm[hb ^ 1][haddr[t4]] = (_Float16)hj[t4];
            }
            if (l == L - 1 && ldx) {
                half4 hv;
                hv[0] = (_Float16)xf.x; hv[1] = (_Float16)xf.y;
                hv[2] = (_Float16)xf.z; hv[3] = (_Float16)xf.w;
                *(half4*)&xperm[(t + 1) & 1][xp_addr(4 * tid)] = hv;
            }
            __syncthreads();
            hb ^= 1;
        }
    }

    if (q == 0) {
#pragma unroll
        for (int t4 = 0; t4 < 4; ++t4)
            out[(size_t)b * 256 + 64 * w + 16 * t4 + n] = hj[t4];
    }
}

extern "C" void kernel_launch(void* const* d_in, const int* in_sizes, int n_in,
                              void* d_out, int out_size, void* d_ws, size_t ws_size,
                              hipStream_t stream) {
    const float* x     = (const float*)d_in[0];
    const float* W_in  = (const float*)d_in[1];
    const float* b_in  = (const float*)d_in[2];
    const float* W_rec = (const float*)d_in[3];
    const float* b_rec = (const float*)d_in[4];
    const float* tau   = (const float*)d_in[5];
    const int*   numl  = (const int*)d_in[6];

    const int H = in_sizes[2];            // 256
    const int I = in_sizes[1] / H;        // 128
    const int B = out_size / H;           // 64
    const int T = in_sizes[0] / (B * I);  // 4096

    ltc_scan<<<B, 256, 0, stream>>>(x, W_in, b_in, W_rec, b_rec, tau,
                                    numl, (float*)d_out, T);
}